// Round 2
// baseline (651.557 us; speedup 1.0000x reference)
//
#include <hip/hip_runtime.h>

// SpectralMapDecomposition:
//   sep[b,i,h,w] = (1/256) * ( ReC[b,h,i]*cos(2*pi*i*w/256) - ImC[b,h,i]*sin(2*pi*i*w/256) )
//   where C[b,h,i] = sum_x img[b,h,x] * exp(-2*pi*j*i*x/256)
//   out = concat([sep (256 ch), mask (32 ch)], axis=1)  -> (8, 288, 256, 256) fp32
//
// HBM-write bound: 604 MB output. Three stream-ordered kernels:
//   1) dft_rows:  2048 blocks, per-row 256-pt DFT, stores C/256 transposed [b][i][h]
//      (stashed inside d_out's b=0 mask-channel region; overwritten last by mask_copy)
//   2) expand:    2048 blocks = (b,i); LDS-staged C column; float4 nt stores
//   3) mask_copy: float4 nt copy of mask channels (runs last -> reclaims the stash)
//
// R1: nontemporal builtins need native vector types, not HIP_vector_type float4.
//     Use ext_vector_type(4) float (same dwordx4 codegen, plus nt flag).

#define TWO_PI_OVER_256 0.02454369260617026f

typedef float vfloat4 __attribute__((ext_vector_type(4)));

__global__ __launch_bounds__(256) void dft_rows_kernel(const float* __restrict__ img,
                                                       float2* __restrict__ Ct) {
    __shared__ float row[256];
    __shared__ float2 cs[256];                 // (cos, sin) fused -> single b64 read
    const int t  = threadIdx.x;
    const int bh = blockIdx.x;                 // b*256 + h
    row[t] = img[(size_t)bh * 256 + t];
    float s, c;
    __sincosf((float)t * TWO_PI_OVER_256, &s, &c);
    cs[t] = make_float2(c, s);
    __syncthreads();

    // thread t computes frequency i = t for this row; twiddle index is exact:
    // angle(i,x) = 2*pi*((i*x) mod 256)/256, walked incrementally k += t (mod 256)
    float re = 0.f, im = 0.f;
    int k = 0;
#pragma unroll 8
    for (int x = 0; x < 256; ++x) {
        const float r = row[x];
        const float2 w = cs[k];
        re = fmaf(r, w.x, re);
        im = fmaf(r, w.y, im);                 // accumulates +sum(r*sin); negate below
        k = (k + t) & 255;
    }
    const int b = bh >> 8;
    const int h = bh & 255;
    // transposed layout Ct[b][i][h] so the expand kernel reads coalesced
    Ct[((size_t)(b * 256 + t)) * 256 + h] =
        make_float2(re * (1.f / 256.f), im * (-1.f / 256.f));
}

__global__ __launch_bounds__(256) void expand_kernel(const float2* __restrict__ Ct,
                                                     float* __restrict__ out) {
    const int t   = threadIdx.x;
    const int blk = blockIdx.x;                // b*256 + i
    const int b   = blk >> 8;
    const int i   = blk & 255;

    __shared__ float2 cp[256];                 // C[b, h=0..255, i] (pre-scaled by 1/256)
    cp[t] = Ct[(size_t)blk * 256 + t];         // coalesced 8B loads

    // each thread owns 4 consecutive w; its cos/sin live in registers for all h
    const int wb = (t & 63) * 4;
    float cw[4], sw[4];
#pragma unroll
    for (int j = 0; j < 4; ++j) {
        const int k = (i * (wb + j)) & 255;    // exact twiddle index
        __sincosf((float)k * TWO_PI_OVER_256, &sw[j], &cw[j]);
    }
    __syncthreads();

    const int hl = t >> 6;                     // 4 h-rows in flight per iteration
    float* __restrict__ obase = out + ((size_t)b * 288 + i) * 65536;
#pragma unroll 4
    for (int it = 0; it < 64; ++it) {
        const int h = it * 4 + hl;
        const float2 cv = cp[h];               // LDS broadcast within each 64-lane team
        vfloat4 v;
        v.x = cv.x * cw[0] - cv.y * sw[0];
        v.y = cv.x * cw[1] - cv.y * sw[1];
        v.z = cv.x * cw[2] - cv.y * sw[2];
        v.w = cv.x * cw[3] - cv.y * sw[3];
        // streamed once, never re-read on GPU -> non-temporal dwordx4 store
        __builtin_nontemporal_store(v, reinterpret_cast<vfloat4*>(obase + (size_t)h * 256 + wb));
    }
}

__global__ __launch_bounds__(256) void mask_copy_kernel(const vfloat4* __restrict__ m,
                                                        vfloat4* __restrict__ out) {
    const size_t e = (size_t)blockIdx.x * 256 + threadIdx.x;  // 0 .. 4194303 (float4 units)
    const size_t b = e >> 19;                                 // 524288 float4 per batch of mask
    const size_t r = e & 524287;
    const vfloat4 v = __builtin_nontemporal_load(&m[b * 524288 + r]);
    __builtin_nontemporal_store(v, &out[b * 4718592 + 4194304 + r]);  // 288ch stride, skip sep
}

extern "C" void kernel_launch(void* const* d_in, const int* in_sizes, int n_in,
                              void* d_out, int out_size, void* d_ws, size_t ws_size,
                              hipStream_t stream) {
    const float* img  = (const float*)d_in[0];   // (8,1,256,256) fp32
    const float* mask = (const float*)d_in[1];   // (8,32,256,256) fp32
    float* out = (float*)d_out;                  // (8,288,256,256) fp32

    // Stash C (4 MB) inside d_out's b=0 mask-channel region [256*65536, 288*65536):
    // expand never writes there (it writes only sep channels), and mask_copy_kernel
    // overwrites it last in stream order. No dependence on ws_size.
    float2* Ct = (float2*)(out + (size_t)256 * 65536);

    dft_rows_kernel<<<2048, 256, 0, stream>>>(img, Ct);
    expand_kernel<<<2048, 256, 0, stream>>>(Ct, out);
    mask_copy_kernel<<<16384, 256, 0, stream>>>((const vfloat4*)mask, (vfloat4*)out);
}

// Round 4
// 650.790 us; speedup vs baseline: 1.0012x; 1.0012x over previous
//
#include <hip/hip_runtime.h>

// SpectralMapDecomposition:
//   sep[b,i,h,w] = (1/256) * ( ReC[b,h,i]*cos(2*pi*i*w/256) - ImC[b,h,i]*sin(2*pi*i*w/256) )
//   where C[b,h,i] = sum_x img[b,h,x] * exp(-2*pi*j*i*x/256)
//   out = concat([sep (256 ch), mask (32 ch)], axis=1)  -> (8, 288, 256, 256) fp32
//
// HBM-write bound: 604 MB output. Three stream-ordered kernels:
//   1) dft_rows:  2048 blocks, per-row 256-pt DFT, stores C/256 transposed [b][i][h]
//      (stashed inside d_out's b=0 mask-channel region; overwritten last by mask_copy)
//   2) expand:    2048 blocks = (b,i); LDS-staged C column; float4 nt stores
//   3) mask_copy: float4 nt copy of mask channels (runs last -> reclaims the stash)
//
// R2: dft_rows was LDS-gather bound (cs[(x*t)&255] -> up to 32-way bank conflicts for
//     x divisible by 16; ~3.5x avg slowdown * 256 iters ~ 85us). Twiddle index advances
//     by a per-thread constant, so replace the gather with an in-register incremental
//     complex rotation (6 VALU/iter, zero LDS), exact __sincosf resync every 32 iters
//     to kill fp32 drift (~3e-6 per 32 steps, tolerance ~1e-3).
// R3: resubmit (GPU acquisition timeout; R2 kernel never measured).

#define TWO_PI_OVER_256 0.02454369260617026f

typedef float vfloat4 __attribute__((ext_vector_type(4)));

__global__ __launch_bounds__(256) void dft_rows_kernel(const float* __restrict__ img,
                                                       float2* __restrict__ Ct) {
    __shared__ float row[256];
    const int t  = threadIdx.x;                // frequency i = t
    const int bh = blockIdx.x;                 // b*256 + h
    row[t] = img[(size_t)bh * 256 + t];

    // per-thread rotation step: e^{+j*2*pi*i/256} (accumulate +sin, negate at store)
    float ci, si;
    __sincosf((float)t * TWO_PI_OVER_256, &si, &ci);
    __syncthreads();

    float re = 0.f, im = 0.f;
    for (int xo = 0; xo < 256; xo += 32) {
        // exact phasor resync at x = xo: angle = 2*pi*((i*xo) mod 256)/256
        const int k = (t * xo) & 255;
        float c, s;
        __sincosf((float)k * TWO_PI_OVER_256, &s, &c);
#pragma unroll
        for (int x2 = 0; x2 < 32; ++x2) {
            const float r = row[xo + x2];      // uniform address -> LDS broadcast (free)
            re = fmaf(r, c, re);
            im = fmaf(r, s, im);
            const float cn = fmaf(c, ci, -s * si);   // rotate phasor by step
            s = fmaf(s, ci, c * si);
            c = cn;
        }
    }
    const int b = bh >> 8;
    const int h = bh & 255;
    // transposed layout Ct[b][i][h] so the expand kernel reads coalesced
    Ct[((size_t)(b * 256 + t)) * 256 + h] =
        make_float2(re * (1.f / 256.f), im * (-1.f / 256.f));
}

__global__ __launch_bounds__(256) void expand_kernel(const float2* __restrict__ Ct,
                                                     float* __restrict__ out) {
    const int t   = threadIdx.x;
    const int blk = blockIdx.x;                // b*256 + i
    const int b   = blk >> 8;
    const int i   = blk & 255;

    __shared__ float2 cp[256];                 // C[b, h=0..255, i] (pre-scaled by 1/256)
    cp[t] = Ct[(size_t)blk * 256 + t];         // coalesced 8B loads

    // each thread owns 4 consecutive w; its cos/sin live in registers for all h
    const int wb = (t & 63) * 4;
    float cw[4], sw[4];
#pragma unroll
    for (int j = 0; j < 4; ++j) {
        const int k = (i * (wb + j)) & 255;    // exact twiddle index
        __sincosf((float)k * TWO_PI_OVER_256, &sw[j], &cw[j]);
    }
    __syncthreads();

    const int hl = t >> 6;                     // 4 h-rows in flight per iteration
    float* __restrict__ obase = out + ((size_t)b * 288 + i) * 65536;
#pragma unroll 4
    for (int it = 0; it < 64; ++it) {
        const int h = it * 4 + hl;
        const float2 cv = cp[h];               // LDS broadcast within each 64-lane team
        vfloat4 v;
        v.x = cv.x * cw[0] - cv.y * sw[0];
        v.y = cv.x * cw[1] - cv.y * sw[1];
        v.z = cv.x * cw[2] - cv.y * sw[2];
        v.w = cv.x * cw[3] - cv.y * sw[3];
        // streamed once, never re-read on GPU -> non-temporal dwordx4 store
        __builtin_nontemporal_store(v, reinterpret_cast<vfloat4*>(obase + (size_t)h * 256 + wb));
    }
}

__global__ __launch_bounds__(256) void mask_copy_kernel(const vfloat4* __restrict__ m,
                                                        vfloat4* __restrict__ out) {
    const size_t e = (size_t)blockIdx.x * 256 + threadIdx.x;  // 0 .. 4194303 (float4 units)
    const size_t b = e >> 19;                                 // 524288 float4 per batch of mask
    const size_t r = e & 524287;
    const vfloat4 v = __builtin_nontemporal_load(&m[b * 524288 + r]);
    __builtin_nontemporal_store(v, &out[b * 4718592 + 4194304 + r]);  // 288ch stride, skip sep
}

extern "C" void kernel_launch(void* const* d_in, const int* in_sizes, int n_in,
                              void* d_out, int out_size, void* d_ws, size_t ws_size,
                              hipStream_t stream) {
    const float* img  = (const float*)d_in[0];   // (8,1,256,256) fp32
    const float* mask = (const float*)d_in[1];   // (8,32,256,256) fp32
    float* out = (float*)d_out;                  // (8,288,256,256) fp32

    // Stash C (4 MB) inside d_out's b=0 mask-channel region [256*65536, 288*65536):
    // expand never writes there (it writes only sep channels), and mask_copy_kernel
    // overwrites it last in stream order. No dependence on ws_size.
    float2* Ct = (float2*)(out + (size_t)256 * 65536);

    dft_rows_kernel<<<2048, 256, 0, stream>>>(img, Ct);
    expand_kernel<<<2048, 256, 0, stream>>>(Ct, out);
    mask_copy_kernel<<<16384, 256, 0, stream>>>((const vfloat4*)mask, (vfloat4*)out);
}

// Round 7
// 649.839 us; speedup vs baseline: 1.0026x; 1.0015x over previous
//
#include <hip/hip_runtime.h>

// SpectralMapDecomposition, fully fused single kernel.
//   sep[b,i,h,w] = (1/256)*( ReC[b,h,i]*cos(2*pi*i*w/256) - ImC[b,h,i]*sin(2*pi*i*w/256) )
//   C[b,h,i] = sum_x img[b,h,x] * exp(-2*pi*j*i*x/256)
//   out = concat([sep (256 ch), mask (32 ch)], axis=1) -> (8, 288, 256, 256) fp32
//
// R4 post-mortem: R2->R4 dft rewrite was NEUTRAL (651.6 -> 650.8) => dft inner loop was
// never the pole. Shared structure was: Ct scatter-store (64x8B at 2KB stride/wave),
// Ct HBM round-trip, 3 serialized launches. Fix: reorganize the DFT by output channel.
//
// Block (b,i) computes C[b,h,i] for ALL h itself (same total FLOPs as row-dft: each
// img element used once per frequency either way) and expands immediately. img[b] is
// 256KB; 256 blocks share it -> L2-resident re-reads (537MB agg / 34.5TB/s ~ 16us,
// hidden under the 537MB write stream). No intermediate, no scatter, one launch.
// Mask-copy blocks ride in the same grid (blockIdx 2048..4095).
//
// Traffic floor: 537w + 67r + 67w + 2r ~ 673MB -> ~107us at the fill-proven 6.29TB/s.
// R5/R6: resubmit (GPU acquisition timeouts; fused kernel never measured).

#define TWO_PI_OVER_256 0.02454369260617026f
#define SR 260   // padded LDS row stride in floats: dft read banks (4*hl+xc+8*x2)%32 -> uniform 2-way (free)

typedef float vfloat4 __attribute__((ext_vector_type(4)));

__global__ __launch_bounds__(256) void fused_kernel(const float* __restrict__ img,
                                                    const vfloat4* __restrict__ mask,
                                                    float* __restrict__ out) {
    const int t   = threadIdx.x;
    const int blk = blockIdx.x;

    if (blk >= 2048) {
        // ---- mask copy: 67MB, 2048 blocks x 256 threads x 8 float4 ----
        const int mb = blk - 2048;
#pragma unroll
        for (int k = 0; k < 8; ++k) {
            const size_t e = (size_t)mb * 256 + t + (size_t)k * 524288;  // 0..4194303
            const size_t b = e >> 19;                                    // 524288 f4/batch
            const size_t r = e & 524287;
            const vfloat4 v = __builtin_nontemporal_load(&mask[b * 524288 + r]);
            __builtin_nontemporal_store(v, (vfloat4*)out + b * 4718592 + 4194304 + r);
        }
        return;
    }

    // ---- fused dft+expand: block owns output channel (b, i) ----
    __shared__ float  rows[32 * SR];   // 32 img rows, padded stride
    __shared__ float2 cp[32];          // C[b, h0..h0+31, i], pre-scaled by 1/256
    const int b = blk >> 8;
    const int i = blk & 255;

    // dft lanes: xc = x-phase (0..7), hl = row within tile (0..31); x = xc + 8*x2
    const int xc = t & 7;
    const int hl = t >> 3;
    float c0, s0, cst, sst;
    __sincosf((float)((i * xc) & 255) * TWO_PI_OVER_256, &s0, &c0);   // phasor start
    __sincosf((float)((i * 8)  & 255) * TWO_PI_OVER_256, &sst, &cst); // step e^{j*2pi*8i/256}

    // expand lanes: thread owns 4 consecutive w for 1-of-4 h rows per iteration
    const int wb  = (t & 63) * 4;
    const int hl2 = t >> 6;
    float cw[4], sw[4];
#pragma unroll
    for (int j = 0; j < 4; ++j) {
        const int k = (i * (wb + j)) & 255;    // exact twiddle index
        __sincosf((float)k * TWO_PI_OVER_256, &sw[j], &cw[j]);
    }

    const float* __restrict__ imgb  = img + (size_t)b * 65536;
    float* __restrict__       obase = out + ((size_t)b * 288 + i) * 65536;

    for (int tile = 0; tile < 8; ++tile) {
        const int h0 = tile * 32;
        // stage 32 rows (32KB) as float2; reads are L2-hits after first touch
        const float2* __restrict__ src = (const float2*)(imgb + h0 * 256);
#pragma unroll
        for (int j = 0; j < 8; ++j) {
            const int idx = t + j * 256;               // 0..2047 (float2 pairs x2)
            const int rr  = idx >> 7;                  // row 0..15  (128 f2/row)
            const int c2  = idx & 127;
            *(float2*)&rows[rr * SR + 2 * c2]        = src[rr * 128 + c2];
            *(float2*)&rows[(rr + 16) * SR + 2 * c2] = src[(rr + 16) * 128 + c2];
        }
        __syncthreads();

        // per-thread partial DFT over x = xc + 8*x2 (in-register phasor, drift ~4e-6)
        float re = 0.f, im = 0.f, c = c0, s = s0;
        const float* __restrict__ rp = &rows[hl * SR + xc];
#pragma unroll
        for (int x2 = 0; x2 < 32; ++x2) {
            const float rv = rp[8 * x2];               // 2-way banked -> free
            re = fmaf(rv, c, re);
            im = fmaf(rv, s, im);                      // +sum(r*sin); negated at cp write
            const float cn = fmaf(c, cst, -s * sst);
            s = fmaf(s, cst, c * sst);
            c = cn;
        }
        // reduce the 8 x-phases (adjacent lanes) -> full C[h0+hl]
        re += __shfl_xor(re, 1); im += __shfl_xor(im, 1);
        re += __shfl_xor(re, 2); im += __shfl_xor(im, 2);
        re += __shfl_xor(re, 4); im += __shfl_xor(im, 4);
        if (xc == 0) cp[hl] = make_float2(re * (1.f / 256.f), im * (-1.f / 256.f));
        __syncthreads();

        // expand these 32 rows: 8 iters x 4KB contiguous nt stores
#pragma unroll
        for (int it2 = 0; it2 < 8; ++it2) {
            const int h = it2 * 4 + hl2;
            const float2 cv = cp[h];                   // wave-uniform -> LDS broadcast
            vfloat4 v;
            v.x = cv.x * cw[0] - cv.y * sw[0];
            v.y = cv.x * cw[1] - cv.y * sw[1];
            v.z = cv.x * cw[2] - cv.y * sw[2];
            v.w = cv.x * cw[3] - cv.y * sw[3];
            __builtin_nontemporal_store(
                v, reinterpret_cast<vfloat4*>(obase + (size_t)(h0 + h) * 256 + wb));
        }
        // rows rewrite next tile is safe: all dft reads completed before the 2nd sync;
        // cp rewrite next tile is safe: expand reads complete before next tile's 1st sync.
    }
}

extern "C" void kernel_launch(void* const* d_in, const int* in_sizes, int n_in,
                              void* d_out, int out_size, void* d_ws, size_t ws_size,
                              hipStream_t stream) {
    const float* img  = (const float*)d_in[0];   // (8,1,256,256) fp32
    const float* mask = (const float*)d_in[1];   // (8,32,256,256) fp32
    float* out = (float*)d_out;                  // (8,288,256,256) fp32

    fused_kernel<<<4096, 256, 0, stream>>>(img, (const vfloat4*)mask, out);
}